// Round 13
// baseline (236.954 us; speedup 1.0000x reference)
//
#include <hip/hip_runtime.h>

#define N_NODES 100000
#define DIM 128
#define NBIN 391      // dest bins of 256 nodes: bin = r >> 8
#define BINSZ 256
#define NCH 391       // fill chunks of 4096 edges
#define CHUNK 4096
#define FCAP 36       // per-(chunk,bin) slots; cell mean 10.49; P(ovf) ~ 3e-4
#define SLOTS (NBIN * FCAP)  // 14076 dwords per chunk plane (56.3 KB)
#define ENTCAP 4608   // per-bin CSR capacity; mean 4092, +8 sigma
#define FSPB 128      // fill spill slots per chunk (never used)
#define SSPB 256      // sort spill slots per bin (never used)

typedef __attribute__((ext_vector_type(8))) short bf16x8;
typedef __attribute__((ext_vector_type(4))) float f32x4;

__device__ __forceinline__ unsigned short f2bf(float f) {
  unsigned u = __builtin_bit_cast(unsigned, f);
  u += 0x7fff + ((u >> 16) & 1);  // RNE
  return (unsigned short)(u >> 16);
}
__device__ __forceinline__ float bfhi(unsigned u) {
  return __builtin_bit_cast(float, u & 0xffff0000u);
}
__device__ __forceinline__ float bflo(unsigned u) {
  return __builtin_bit_cast(float, u << 16);
}

// ---------------------------------------------------------------------------
// Kernel 1: LDS-staged binning, 4096-edge chunks (16 edges/thread, 4x int4
// batched loads) + 32 trailing blocks pre-convert W fp32->bf16 into Wb.
// ---------------------------------------------------------------------------
__global__ __launch_bounds__(256, 2) void fill_kernel(
    const int* __restrict__ rows, const int* __restrict__ cols,
    int* __restrict__ counts, unsigned* __restrict__ binned,
    int* __restrict__ fspillc, int2* __restrict__ fspill, int n_edges,
    const float* __restrict__ W1, const float* __restrict__ W2,
    unsigned short* __restrict__ Wb) {
  const int tid = threadIdx.x;
  if (blockIdx.x >= NCH) {
    // -------- wconv path: 32 blocks x 256 threads = 8192 float4 --------
    const int v = (blockIdx.x - NCH) * 256 + tid;
    const int j = v >> 5, q = v & 31;
    const float* Wrow =
        (j < 128) ? (W1 + (size_t)j * DIM) : (W2 + (size_t)(j - 128) * DIM);
    const float4 val = *(const float4*)(Wrow + 4 * q);
    const unsigned lo = (unsigned)f2bf(val.x) | ((unsigned)f2bf(val.y) << 16);
    const unsigned hi = (unsigned)f2bf(val.z) | ((unsigned)f2bf(val.w) << 16);
    *(uint2*)(Wb + (size_t)j * DIM + 4 * q) = make_uint2(lo, hi);
    return;
  }

  __shared__ unsigned buf[SLOTS];  // 56.3 KB, layout b*FCAP + slot
  __shared__ int lcnt[NBIN];
  __shared__ int fsc;
  const int ch = blockIdx.x;
  for (int i = tid; i < NBIN; i += 256) lcnt[i] = 0;
  if (tid == 0) fsc = 0;
  __syncthreads();

  const int e0 = ch * CHUNK + tid * 16;
  int rv[16], cv[16];
  int nval;
  if (e0 + 16 <= n_edges) {
#pragma unroll
    for (int q = 0; q < 4; ++q) {
      *(int4*)&rv[4 * q] = *(const int4*)(rows + e0 + 4 * q);
      *(int4*)&cv[4 * q] = *(const int4*)(cols + e0 + 4 * q);
    }
    nval = 16;
  } else {
    nval = 0;
    for (int k = 0; k < 16; ++k)
      if (e0 + k < n_edges) {
        rv[nval] = rows[e0 + k];
        cv[nval] = cols[e0 + k];
        ++nval;
      }
  }
  for (int k = 0; k < nval; ++k) {
    const int r = rv[k];
    const int b = r >> 8;
    const unsigned payload = ((unsigned)(r & 255) << 17) | (unsigned)cv[k];
    const int slot = atomicAdd(&lcnt[b], 1);
    if (slot < FCAP) {
      buf[b * FCAP + slot] = payload;
    } else {  // ~never
      const int sp = atomicAdd(&fsc, 1);
      if (sp < FSPB) fspill[ch * FSPB + sp] = make_int2(r, cv[k]);
    }
  }
  __syncthreads();

  // dense coalesced flush
  unsigned* dst = binned + (size_t)ch * SLOTS;
  for (int i4 = tid; i4 < SLOTS / 4; i4 += 256)
    *(uint4*)(dst + 4 * i4) = *(const uint4*)&buf[4 * i4];
  for (int b = tid; b < NBIN; b += 256)
    counts[(size_t)ch * NBIN + b] = min(lcnt[b], FCAP);
  if (tid == 0) fspillc[ch] = min(fsc, FSPB);  // ALWAYS written
}

// ---------------------------------------------------------------------------
// Kernel 2: dual GEMM via bf16 MFMA (R12-measured-good, unchanged).
// launch_bounds(256,2): VGPR cap 256 >= ~220 live set -> no scratch spill
// (R11 lesson).  B frags = direct 16B loads from pre-converted Wb.
// ---------------------------------------------------------------------------
__global__ __launch_bounds__(256, 2) void gemm_kernel(
    const float* __restrict__ x, const unsigned short* __restrict__ Wb,
    unsigned short* __restrict__ selfb, unsigned short* __restrict__ neigh) {
  __shared__ unsigned short xs[128 * 136];  // 34.8 KB

  const int tid = threadIdx.x;
  const int lane = tid & 63;
  const int w = tid >> 6;
  const int nb = blockIdx.x * 128;
  const int quad = lane >> 4;
  const int l15 = lane & 15;

  bf16x8 bfrag[4][4];
#pragma unroll
  for (int nt = 0; nt < 4; ++nt) {
    const int j = w * 64 + nt * 16 + l15;
#pragma unroll
    for (int ks = 0; ks < 4; ++ks)
      bfrag[nt][ks] =
          *(const bf16x8*)(Wb + (size_t)j * DIM + ks * 32 + quad * 8);
  }

#pragma unroll
  for (int half = 0; half < 2; ++half) {
    float4 av[8];
#pragma unroll
    for (int it = 0; it < 8; ++it) {
      const int v = tid + (half * 8 + it) * 256;
      const int m = v >> 5, q = v & 31;
      av[it] = (nb + m < N_NODES)
                   ? *(const float4*)(x + (size_t)(nb + m) * DIM + 4 * q)
                   : make_float4(0.f, 0.f, 0.f, 0.f);
    }
#pragma unroll
    for (int it = 0; it < 8; ++it) {
      const int v = tid + (half * 8 + it) * 256;
      const int m = v >> 5, q = v & 31;
      const unsigned lo =
          (unsigned)f2bf(av[it].x) | ((unsigned)f2bf(av[it].y) << 16);
      const unsigned hi =
          (unsigned)f2bf(av[it].z) | ((unsigned)f2bf(av[it].w) << 16);
      *(uint2*)&xs[m * 136 + 4 * q] = make_uint2(lo, hi);
    }
  }
  __syncthreads();

  f32x4 acc[8][4];
#pragma unroll
  for (int mt = 0; mt < 8; ++mt)
#pragma unroll
    for (int nt = 0; nt < 4; ++nt) acc[mt][nt] = (f32x4){0.f, 0.f, 0.f, 0.f};

#pragma unroll
  for (int ks = 0; ks < 4; ++ks) {
#pragma unroll
    for (int mt = 0; mt < 8; ++mt) {
      const bf16x8 afrag =
          *(const bf16x8*)&xs[(mt * 16 + l15) * 136 + ks * 32 + quad * 8];
#pragma unroll
      for (int nt = 0; nt < 4; ++nt)
        acc[mt][nt] = __builtin_amdgcn_mfma_f32_16x16x32_bf16(
            afrag, bfrag[nt][ks], acc[mt][nt], 0, 0, 0);
    }
  }

#pragma unroll
  for (int h = 0; h < 2; ++h) {
    __syncthreads();
    if ((w >> 1) == h) {
#pragma unroll
      for (int mt = 0; mt < 8; ++mt)
#pragma unroll
        for (int nt = 0; nt < 4; ++nt) {
          const int col = (w & 1) * 64 + nt * 16 + l15;
#pragma unroll
          for (int r = 0; r < 4; ++r)
            xs[(mt * 16 + quad * 4 + r) * 136 + col] = f2bf(acc[mt][nt][r]);
        }
    }
    __syncthreads();
    unsigned short* dst = h ? neigh : selfb;
#pragma unroll
    for (int it = 0; it < 8; ++it) {
      const int v = it * 256 + tid;
      const int row = v >> 4, q = v & 15;
      if (nb + row < N_NODES)
        *(uint4*)(dst + (size_t)(nb + row) * DIM + 8 * q) =
            *(const uint4*)&xs[row * 136 + 8 * q];
    }
  }
}

// ---------------------------------------------------------------------------
// Kernel 3: per-bin counting sort -> exact CSR.  NCH=391: shorter scan
// (9 rounds), compaction = 9 unconditional uint4 loads per segment.
// ---------------------------------------------------------------------------
__global__ __launch_bounds__(256, 3) void sort_kernel(
    const int* __restrict__ counts, const unsigned* __restrict__ binned,
    int* __restrict__ csr_cols, int* __restrict__ row_ptr,
    int* __restrict__ degs, int* __restrict__ sspillc,
    int2* __restrict__ sspill) {
  __shared__ int segc[NCH];            // 1.6 KB
  __shared__ int ssa[NCH], ssb[NCH];   // 3.1 KB
  __shared__ unsigned entbuf[ENTCAP];  // 18.4 KB
  __shared__ int outbuf[ENTCAP];       // 18.4 KB
  __shared__ int hist[BINSZ], hsa[BINSZ], hsb[BINSZ], cur[BINSZ];  // 4 KB
  __shared__ int ssc;

  const int tid = threadIdx.x;
  const int bin = blockIdx.x;
  if (tid == 0) ssc = 0;

  for (int i = tid; i < NCH; i += 256) {
    const int c = counts[(size_t)i * NBIN + bin];  // independent gathers
    segc[i] = c;
    ssa[i] = c;
  }
  __syncthreads();
  for (int off = 1; off < NCH; off <<= 1) {
    for (int i = tid; i < NCH; i += 256)
      ssb[i] = ssa[i] + ((i >= off) ? ssa[i - off] : 0);
    __syncthreads();
    for (int i = tid; i < NCH; i += 256) ssa[i] = ssb[i];
    __syncthreads();
  }

  // compaction: 391 segs x 9 uint4 = 3519 unconditional 16B loads
  const unsigned* bbase = binned + (size_t)bin * FCAP;
  for (int u = tid; u < NCH * (FCAP / 4); u += 256) {
    const int ch = u / 9;
    const int q = u - ch * 9;
    uint4 v4 = *(const uint4*)(bbase + (size_t)ch * SLOTS + 4 * q);
    const int cnt = segc[ch];
    const int base = ssa[ch] - cnt;  // exclusive prefix
    const unsigned vals[4] = {v4.x, v4.y, v4.z, v4.w};
#pragma unroll
    for (int j = 0; j < 4; ++j) {
      const int slot = 4 * q + j;
      if (slot < cnt) {
        const int pos = base + slot;
        if (pos < ENTCAP) {
          entbuf[pos] = vals[j];
        } else {  // ~never
          const int sp = atomicAdd(&ssc, 1);
          if (sp < SSPB)
            sspill[bin * SSPB + sp] = make_int2(
                (bin << 8) | (int)(vals[j] >> 17), (int)(vals[j] & 0x1FFFFu));
        }
      }
    }
  }
  hist[tid] = 0;
  __syncthreads();

  const int total = min(ssa[NCH - 1], ENTCAP);
  for (int i = tid; i < total; i += 256) atomicAdd(&hist[entbuf[i] >> 17], 1);
  __syncthreads();

  hsa[tid] = hist[tid];
  __syncthreads();
  for (int off = 1; off < BINSZ; off <<= 1) {
    hsb[tid] = hsa[tid] + ((tid >= off) ? hsa[tid - off] : 0);
    __syncthreads();
    hsa[tid] = hsb[tid];
    __syncthreads();
  }

  const int gbase = bin * ENTCAP;
  {
    const int start = hsa[tid] - hist[tid];
    cur[tid] = start;
    const int node = (bin << 8) | tid;
    if (node < N_NODES) {
      row_ptr[node] = gbase + start;
      degs[node] = hist[tid];
    }
  }
  __syncthreads();

  for (int i = tid; i < total; i += 256) {
    const unsigned p = entbuf[i];
    const int pos = atomicAdd(&cur[p >> 17], 1);
    outbuf[pos] = (int)(p & 0x1FFFFu);
  }
  __syncthreads();

  for (int i = tid; i < total; i += 256) csr_cols[gbase + i] = outbuf[i];
  if (tid == 0) sspillc[bin] = min(ssc, SSPB);  // ALWAYS written
}

// ---------------------------------------------------------------------------
// Kernel 4: persistent wave-per-node gather (bf16) + self(bf16) + ReLU.
// Unchanged from R12 (structural floor: 8-XCD L2 replication of neigh).
// ---------------------------------------------------------------------------
__global__ __launch_bounds__(256) void agg_kernel(
    const int* __restrict__ row_ptr, const int* __restrict__ degs,
    const int* __restrict__ csr_cols, const unsigned short* __restrict__ neigh,
    const unsigned short* __restrict__ selfb, const int* __restrict__ fspillc,
    const int2* __restrict__ fspill, const int* __restrict__ sspillc,
    const int2* __restrict__ sspill, float* __restrict__ out) {
  __shared__ int has_spill;
  const int tid = threadIdx.x;
  if (tid == 0) has_spill = 0;
  __syncthreads();
  for (int i = tid; i < NCH + NBIN; i += 256) {
    const int v = (i < NCH) ? fspillc[i] : sspillc[i - NCH];
    if (v) atomicOr(&has_spill, 1);
  }
  __syncthreads();
  const bool spilled = has_spill != 0;

  const int l = tid & 63;
  const int wid = blockIdx.x * 4 + (tid >> 6);
  const int stride = gridDim.x * 4;
  const unsigned* ng = (const unsigned*)neigh;

  for (int node = wid; node < N_NODES; node += stride) {
    const int deg = degs[node];
    const int* cl = csr_cols + row_ptr[node];
    const unsigned s = ((const unsigned*)selfb)[(size_t)node * 64 + l];

    float ax = 0.f, ay = 0.f;
    int d = 0;
    for (; d + 8 <= deg; d += 8) {
      unsigned uv[8];
#pragma unroll
      for (int k = 0; k < 8; ++k) uv[k] = ng[(size_t)cl[d + k] * 64 + l];
#pragma unroll
      for (int k = 0; k < 8; ++k) {
        ax += bflo(uv[k]);
        ay += bfhi(uv[k]);
      }
    }
    const int rem = deg - d;
    if (rem) {
      unsigned uv[8];
      const int cdup = cl[d];  // dup row stays in-cache
#pragma unroll
      for (int k = 0; k < 8; ++k) {
        const int ci = (k < rem) ? cl[d + k] : cdup;
        uv[k] = ng[(size_t)ci * 64 + l];
      }
#pragma unroll
      for (int k = 0; k < 8; ++k) {
        if (k < rem) {  // wave-uniform mask
          ax += bflo(uv[k]);
          ay += bfhi(uv[k]);
        }
      }
    }

    if (spilled) {  // never taken in practice
      for (int bi = 0; bi < NCH; ++bi) {
        const int n = min(fspillc[bi], FSPB);
        for (int i = 0; i < n; ++i) {
          const int2 e = fspill[bi * FSPB + i];
          if (e.x == node) {
            const unsigned u = ng[(size_t)e.y * 64 + l];
            ax += bflo(u);
            ay += bfhi(u);
          }
        }
      }
      for (int bi = 0; bi < NBIN; ++bi) {
        const int n = min(sspillc[bi], SSPB);
        for (int i = 0; i < n; ++i) {
          const int2 e = sspill[bi * SSPB + i];
          if (e.x == node) {
            const unsigned u = ng[(size_t)e.y * 64 + l];
            ax += bflo(u);
            ay += bfhi(u);
          }
        }
      }
    }

    float2 o;
    o.x = fmaxf(bflo(s) + ax, 0.f);
    o.y = fmaxf(bfhi(s) + ay, 0.f);
    *(float2*)(out + (size_t)node * DIM + 2 * l) = o;
  }
}

extern "C" void kernel_launch(void* const* d_in, const int* in_sizes, int n_in,
                              void* d_out, int out_size, void* d_ws,
                              size_t ws_size, hipStream_t stream) {
  const float* x = (const float*)d_in[0];
  const int* edge_index = (const int*)d_in[1];  // (2,E): [0]=row(dst), [1]=col(src)
  const float* W1 = (const float*)d_in[2];
  const float* W2 = (const float*)d_in[3];
  float* out = (float*)d_out;

  const int n_edges = in_sizes[1] / 2;
  const int* rows = edge_index;
  const int* cols = edge_index + n_edges;

  // ws layout (~82 MB): selfb 25.6 | neigh 25.6 | binned 22.0 | counts 0.6 |
  // csr 7.2 | row_ptr 0.4 | degs 0.4 | fspillc | fspill | sspillc | sspill |
  // Wb 64K
  char* p = (char*)d_ws;
  unsigned short* selfb = (unsigned short*)p;
  p += (size_t)N_NODES * DIM * 2;
  unsigned short* neigh = (unsigned short*)p;
  p += (size_t)N_NODES * DIM * 2;
  unsigned* binned = (unsigned*)p;
  p += (size_t)NCH * SLOTS * 4;
  int* counts = (int*)p;
  p += (size_t)NCH * NBIN * 4;
  int* csr_cols = (int*)p;
  p += (size_t)NBIN * ENTCAP * 4;
  int* row_ptr = (int*)p;
  p += (size_t)N_NODES * 4;
  int* degs = (int*)p;
  p += (size_t)N_NODES * 4;
  int* fspillc = (int*)p;
  p += 4096;
  int2* fspill = (int2*)p;
  p += (size_t)NCH * FSPB * sizeof(int2);
  int* sspillc = (int*)p;
  p += 4096;
  int2* sspill = (int2*)p;
  p += (size_t)NBIN * SSPB * sizeof(int2);
  unsigned short* Wb = (unsigned short*)p;  // 64 KB

  // fill first (its 32 trailing blocks pre-convert W for gemm)
  fill_kernel<<<NCH + 32, 256, 0, stream>>>(rows, cols, counts, binned,
                                            fspillc, fspill, n_edges, W1, W2,
                                            Wb);
  gemm_kernel<<<(N_NODES + 127) / 128, 256, 0, stream>>>(x, Wb, selfb, neigh);
  sort_kernel<<<NBIN, 256, 0, stream>>>(counts, binned, csr_cols, row_ptr,
                                        degs, sspillc, sspill);
  agg_kernel<<<2048, 256, 0, stream>>>(row_ptr, degs, csr_cols, neigh, selfb,
                                       fspillc, fspill, sspillc, sspill, out);
}

// Round 14
// 232.174 us; speedup vs baseline: 1.0206x; 1.0206x over previous
//
#include <hip/hip_runtime.h>

#define N_NODES 100000
#define DIM 128
#define NBIN 391      // dest bins of 256 nodes: bin = r >> 8
#define BINSZ 256
#define NCH 782       // fill chunks of 2048 edges (R12-measured-best)
#define CHUNK 2048
#define FCAP 24       // per-(chunk,bin) slots; cell mean 5.24
#define SLOTS (NBIN * FCAP)  // 9384 dwords per chunk plane
#define ENTCAP 4608   // per-bin CSR capacity; mean 4092, +8 sigma
#define FSPB 128      // fill spill slots per chunk (never used)
#define SSPB 256      // sort spill slots per bin (never used)
#define NGEMM 782     // gemm tiles of 128 nodes

typedef __attribute__((ext_vector_type(8))) short bf16x8;
typedef __attribute__((ext_vector_type(4))) float f32x4;

__device__ __forceinline__ unsigned short f2bf(float f) {
  unsigned u = __builtin_bit_cast(unsigned, f);
  u += 0x7fff + ((u >> 16) & 1);  // RNE
  return (unsigned short)(u >> 16);
}
__device__ __forceinline__ float bfhi(unsigned u) {
  return __builtin_bit_cast(float, u & 0xffff0000u);
}
__device__ __forceinline__ float bflo(unsigned u) {
  return __builtin_bit_cast(float, u << 16);
}

// ---------------------------------------------------------------------------
// Kernel 1: LDS-staged binning (R12-measured-best: 2048-edge chunks, FCAP 24,
// 4 blocks/CU) + 32 trailing blocks pre-convert W fp32->bf16 into Wb.
// ---------------------------------------------------------------------------
__global__ __launch_bounds__(256, 4) void fill_kernel(
    const int* __restrict__ rows, const int* __restrict__ cols,
    int* __restrict__ counts, unsigned* __restrict__ binned,
    int* __restrict__ fspillc, int2* __restrict__ fspill, int n_edges,
    const float* __restrict__ W1, const float* __restrict__ W2,
    unsigned short* __restrict__ Wb) {
  const int tid = threadIdx.x;
  if (blockIdx.x >= NCH) {
    // -------- wconv path: 32 blocks x 256 threads = 8192 float4 --------
    const int v = (blockIdx.x - NCH) * 256 + tid;
    const int j = v >> 5, q = v & 31;
    const float* Wrow =
        (j < 128) ? (W1 + (size_t)j * DIM) : (W2 + (size_t)(j - 128) * DIM);
    const float4 val = *(const float4*)(Wrow + 4 * q);
    const unsigned lo = (unsigned)f2bf(val.x) | ((unsigned)f2bf(val.y) << 16);
    const unsigned hi = (unsigned)f2bf(val.z) | ((unsigned)f2bf(val.w) << 16);
    *(uint2*)(Wb + (size_t)j * DIM + 4 * q) = make_uint2(lo, hi);
    return;
  }

  __shared__ unsigned buf[SLOTS];  // 37.5 KB, layout b*FCAP + slot
  __shared__ int lcnt[NBIN];
  __shared__ int fsc;
  const int ch = blockIdx.x;
  for (int i = tid; i < NBIN; i += 256) lcnt[i] = 0;
  if (tid == 0) fsc = 0;
  __syncthreads();

  const int e0 = ch * CHUNK + tid * 8;
  int rv[8], cv[8];
  int nval;
  if (e0 + 8 <= n_edges) {
    *(int4*)&rv[0] = *(const int4*)(rows + e0);
    *(int4*)&rv[4] = *(const int4*)(rows + e0 + 4);
    *(int4*)&cv[0] = *(const int4*)(cols + e0);
    *(int4*)&cv[4] = *(const int4*)(cols + e0 + 4);
    nval = 8;
  } else {
    nval = 0;
    for (int k = 0; k < 8; ++k)
      if (e0 + k < n_edges) {
        rv[nval] = rows[e0 + k];
        cv[nval] = cols[e0 + k];
        ++nval;
      }
  }
  for (int k = 0; k < nval; ++k) {
    const int r = rv[k];
    const int b = r >> 8;
    const unsigned payload = ((unsigned)(r & 255) << 17) | (unsigned)cv[k];
    const int slot = atomicAdd(&lcnt[b], 1);
    if (slot < FCAP) {
      buf[b * FCAP + slot] = payload;
    } else {  // ~never
      const int sp = atomicAdd(&fsc, 1);
      if (sp < FSPB) fspill[ch * FSPB + sp] = make_int2(r, cv[k]);
    }
  }
  __syncthreads();

  // dense coalesced flush
  unsigned* dst = binned + (size_t)ch * SLOTS;
  for (int i4 = tid; i4 < SLOTS / 4; i4 += 256)
    *(uint4*)(dst + 4 * i4) = *(const uint4*)&buf[4 * i4];
  for (int b = tid; b < NBIN; b += 256)
    counts[(size_t)ch * NBIN + b] = min(lcnt[b], FCAP);
  if (tid == 0) fspillc[ch] = min(fsc, FSPB);  // ALWAYS written
}

// ---------------------------------------------------------------------------
// Kernel 2: FUSED gemm + sort (independent work, both depend only on fill).
// Block routing: groups of 3 = 2 gemm tiles + 1 sort bin (exact 2:1 ratio,
// interleaved so a CU hosts one of each -> MFMA/VALU overlaps sort's
// scan/memory phases).  Both paths want 2 blocks/CU + big LDS, unlike R9's
// failed fusion.  launch_bounds(256,2): no spill (R11 lesson).
// ---------------------------------------------------------------------------
union FusedSh {
  unsigned short xs[128 * 136];  // gemm: 34.8 KB
  struct {
    int segc[NCH], ssa[NCH], ssb[NCH];         // 9.4 KB
    unsigned entbuf[ENTCAP];                    // 18.4 KB
    int outbuf[ENTCAP];                         // 18.4 KB
    int hist[BINSZ], hsa[BINSZ], hsb[BINSZ], cur[BINSZ];  // 4 KB
    int ssc;
  } s;  // sort: 50.3 KB
};

__global__ __launch_bounds__(256, 2) void gemmsort_kernel(
    const float* __restrict__ x, const unsigned short* __restrict__ Wb,
    unsigned short* __restrict__ selfb, unsigned short* __restrict__ neigh,
    const int* __restrict__ counts, const unsigned* __restrict__ binned,
    int* __restrict__ csr_cols, int* __restrict__ row_ptr,
    int* __restrict__ degs, int* __restrict__ sspillc,
    int2* __restrict__ sspill) {
  __shared__ FusedSh sh;
  const int tid = threadIdx.x;
  const int g = blockIdx.x / 3, r3 = blockIdx.x % 3;

  if (r3 < 2) {
    // ================= GEMM path: tile t of 128 nodes =================
    const int t = g * 2 + r3;
    const int lane = tid & 63;
    const int w = tid >> 6;
    const int nb = t * 128;
    const int quad = lane >> 4;
    const int l15 = lane & 15;

    bf16x8 bfrag[4][4];
#pragma unroll
    for (int nt = 0; nt < 4; ++nt) {
      const int j = w * 64 + nt * 16 + l15;
#pragma unroll
      for (int ks = 0; ks < 4; ++ks)
        bfrag[nt][ks] =
            *(const bf16x8*)(Wb + (size_t)j * DIM + ks * 32 + quad * 8);
    }

#pragma unroll
    for (int half = 0; half < 2; ++half) {
      float4 av[8];
#pragma unroll
      for (int it = 0; it < 8; ++it) {
        const int v = tid + (half * 8 + it) * 256;
        const int m = v >> 5, q = v & 31;
        av[it] = (nb + m < N_NODES)
                     ? *(const float4*)(x + (size_t)(nb + m) * DIM + 4 * q)
                     : make_float4(0.f, 0.f, 0.f, 0.f);
      }
#pragma unroll
      for (int it = 0; it < 8; ++it) {
        const int v = tid + (half * 8 + it) * 256;
        const int m = v >> 5, q = v & 31;
        const unsigned lo =
            (unsigned)f2bf(av[it].x) | ((unsigned)f2bf(av[it].y) << 16);
        const unsigned hi =
            (unsigned)f2bf(av[it].z) | ((unsigned)f2bf(av[it].w) << 16);
        *(uint2*)&sh.xs[m * 136 + 4 * q] = make_uint2(lo, hi);
      }
    }
    __syncthreads();

    f32x4 acc[8][4];
#pragma unroll
    for (int mt = 0; mt < 8; ++mt)
#pragma unroll
      for (int nt = 0; nt < 4; ++nt) acc[mt][nt] = (f32x4){0.f, 0.f, 0.f, 0.f};

#pragma unroll
    for (int ks = 0; ks < 4; ++ks) {
#pragma unroll
      for (int mt = 0; mt < 8; ++mt) {
        const bf16x8 afrag =
            *(const bf16x8*)&sh.xs[(mt * 16 + l15) * 136 + ks * 32 + quad * 8];
#pragma unroll
        for (int nt = 0; nt < 4; ++nt)
          acc[mt][nt] = __builtin_amdgcn_mfma_f32_16x16x32_bf16(
              afrag, bfrag[nt][ks], acc[mt][nt], 0, 0, 0);
      }
    }

#pragma unroll
    for (int h = 0; h < 2; ++h) {
      __syncthreads();
      if ((w >> 1) == h) {
#pragma unroll
        for (int mt = 0; mt < 8; ++mt)
#pragma unroll
          for (int nt = 0; nt < 4; ++nt) {
            const int col = (w & 1) * 64 + nt * 16 + l15;
#pragma unroll
            for (int r = 0; r < 4; ++r)
              sh.xs[(mt * 16 + quad * 4 + r) * 136 + col] =
                  f2bf(acc[mt][nt][r]);
          }
      }
      __syncthreads();
      unsigned short* dst = h ? neigh : selfb;
#pragma unroll
      for (int it = 0; it < 8; ++it) {
        const int v = it * 256 + tid;
        const int row = v >> 4, q = v & 15;
        if (nb + row < N_NODES)
          *(uint4*)(dst + (size_t)(nb + row) * DIM + 8 * q) =
              *(const uint4*)&sh.xs[row * 136 + 8 * q];
      }
    }
  } else {
    // ================= SORT path: bin g (256 nodes) =================
    const int bin = g;
    if (tid == 0) sh.s.ssc = 0;

    for (int i = tid; i < NCH; i += 256) {
      const int c = counts[(size_t)i * NBIN + bin];  // independent gathers
      sh.s.segc[i] = c;
      sh.s.ssa[i] = c;
    }
    __syncthreads();
    for (int off = 1; off < NCH; off <<= 1) {
      for (int i = tid; i < NCH; i += 256)
        sh.s.ssb[i] = sh.s.ssa[i] + ((i >= off) ? sh.s.ssa[i - off] : 0);
      __syncthreads();
      for (int i = tid; i < NCH; i += 256) sh.s.ssa[i] = sh.s.ssb[i];
      __syncthreads();
    }

    // compaction: 782 segs x 6 uint4 = 4692 unconditional 16B loads
    const unsigned* bbase = binned + (size_t)bin * FCAP;
    for (int u = tid; u < NCH * (FCAP / 4); u += 256) {
      const int ch = u / 6;
      const int q = u - ch * 6;
      uint4 v4 = *(const uint4*)(bbase + (size_t)ch * SLOTS + 4 * q);
      const int cnt = sh.s.segc[ch];
      const int base = sh.s.ssa[ch] - cnt;  // exclusive prefix
      const unsigned vals[4] = {v4.x, v4.y, v4.z, v4.w};
#pragma unroll
      for (int j = 0; j < 4; ++j) {
        const int slot = 4 * q + j;
        if (slot < cnt) {
          const int pos = base + slot;
          if (pos < ENTCAP) {
            sh.s.entbuf[pos] = vals[j];
          } else {  // ~never
            const int sp = atomicAdd(&sh.s.ssc, 1);
            if (sp < SSPB)
              sspill[bin * SSPB + sp] =
                  make_int2((bin << 8) | (int)(vals[j] >> 17),
                            (int)(vals[j] & 0x1FFFFu));
          }
        }
      }
    }
    sh.s.hist[tid] = 0;
    __syncthreads();

    const int total = min(sh.s.ssa[NCH - 1], ENTCAP);
    for (int i = tid; i < total; i += 256)
      atomicAdd(&sh.s.hist[sh.s.entbuf[i] >> 17], 1);
    __syncthreads();

    sh.s.hsa[tid] = sh.s.hist[tid];
    __syncthreads();
    for (int off = 1; off < BINSZ; off <<= 1) {
      sh.s.hsb[tid] = sh.s.hsa[tid] + ((tid >= off) ? sh.s.hsa[tid - off] : 0);
      __syncthreads();
      sh.s.hsa[tid] = sh.s.hsb[tid];
      __syncthreads();
    }

    const int gbase = bin * ENTCAP;
    {
      const int start = sh.s.hsa[tid] - sh.s.hist[tid];
      sh.s.cur[tid] = start;
      const int node = (bin << 8) | tid;
      if (node < N_NODES) {
        row_ptr[node] = gbase + start;
        degs[node] = sh.s.hist[tid];
      }
    }
    __syncthreads();

    for (int i = tid; i < total; i += 256) {
      const unsigned p = sh.s.entbuf[i];
      const int pos = atomicAdd(&sh.s.cur[p >> 17], 1);
      sh.s.outbuf[pos] = (int)(p & 0x1FFFFu);
    }
    __syncthreads();

    for (int i = tid; i < total; i += 256)
      csr_cols[gbase + i] = sh.s.outbuf[i];
    if (tid == 0) sspillc[bin] = min(sh.s.ssc, SSPB);  // ALWAYS written
  }
}

// ---------------------------------------------------------------------------
// Kernel 3: persistent wave-per-node gather (bf16) + self(bf16) + ReLU.
// Unchanged from R12 (structural floor: 8-XCD L2 replication of neigh).
// ---------------------------------------------------------------------------
__global__ __launch_bounds__(256) void agg_kernel(
    const int* __restrict__ row_ptr, const int* __restrict__ degs,
    const int* __restrict__ csr_cols, const unsigned short* __restrict__ neigh,
    const unsigned short* __restrict__ selfb, const int* __restrict__ fspillc,
    const int2* __restrict__ fspill, const int* __restrict__ sspillc,
    const int2* __restrict__ sspill, float* __restrict__ out) {
  __shared__ int has_spill;
  const int tid = threadIdx.x;
  if (tid == 0) has_spill = 0;
  __syncthreads();
  for (int i = tid; i < NCH + NBIN; i += 256) {
    const int v = (i < NCH) ? fspillc[i] : sspillc[i - NCH];
    if (v) atomicOr(&has_spill, 1);
  }
  __syncthreads();
  const bool spilled = has_spill != 0;

  const int l = tid & 63;
  const int wid = blockIdx.x * 4 + (tid >> 6);
  const int stride = gridDim.x * 4;
  const unsigned* ng = (const unsigned*)neigh;

  for (int node = wid; node < N_NODES; node += stride) {
    const int deg = degs[node];
    const int* cl = csr_cols + row_ptr[node];
    const unsigned s = ((const unsigned*)selfb)[(size_t)node * 64 + l];

    float ax = 0.f, ay = 0.f;
    int d = 0;
    for (; d + 8 <= deg; d += 8) {
      unsigned uv[8];
#pragma unroll
      for (int k = 0; k < 8; ++k) uv[k] = ng[(size_t)cl[d + k] * 64 + l];
#pragma unroll
      for (int k = 0; k < 8; ++k) {
        ax += bflo(uv[k]);
        ay += bfhi(uv[k]);
      }
    }
    const int rem = deg - d;
    if (rem) {
      unsigned uv[8];
      const int cdup = cl[d];  // dup row stays in-cache
#pragma unroll
      for (int k = 0; k < 8; ++k) {
        const int ci = (k < rem) ? cl[d + k] : cdup;
        uv[k] = ng[(size_t)ci * 64 + l];
      }
#pragma unroll
      for (int k = 0; k < 8; ++k) {
        if (k < rem) {  // wave-uniform mask
          ax += bflo(uv[k]);
          ay += bfhi(uv[k]);
        }
      }
    }

    if (spilled) {  // never taken in practice
      for (int bi = 0; bi < NCH; ++bi) {
        const int n = min(fspillc[bi], FSPB);
        for (int i = 0; i < n; ++i) {
          const int2 e = fspill[bi * FSPB + i];
          if (e.x == node) {
            const unsigned u = ng[(size_t)e.y * 64 + l];
            ax += bflo(u);
            ay += bfhi(u);
          }
        }
      }
      for (int bi = 0; bi < NBIN; ++bi) {
        const int n = min(sspillc[bi], SSPB);
        for (int i = 0; i < n; ++i) {
          const int2 e = sspill[bi * SSPB + i];
          if (e.x == node) {
            const unsigned u = ng[(size_t)e.y * 64 + l];
            ax += bflo(u);
            ay += bfhi(u);
          }
        }
      }
    }

    float2 o;
    o.x = fmaxf(bflo(s) + ax, 0.f);
    o.y = fmaxf(bfhi(s) + ay, 0.f);
    *(float2*)(out + (size_t)node * DIM + 2 * l) = o;
  }
}

extern "C" void kernel_launch(void* const* d_in, const int* in_sizes, int n_in,
                              void* d_out, int out_size, void* d_ws,
                              size_t ws_size, hipStream_t stream) {
  const float* x = (const float*)d_in[0];
  const int* edge_index = (const int*)d_in[1];  // (2,E): [0]=row(dst), [1]=col(src)
  const float* W1 = (const float*)d_in[2];
  const float* W2 = (const float*)d_in[3];
  float* out = (float*)d_out;

  const int n_edges = in_sizes[1] / 2;
  const int* rows = edge_index;
  const int* cols = edge_index + n_edges;

  // ws layout (~91 MB): selfb 25.6 | neigh 25.6 | binned 29.4 | counts 1.2 |
  // csr 7.2 | row_ptr 0.4 | degs 0.4 | fspillc | fspill | sspillc | sspill |
  // Wb 64K
  char* p = (char*)d_ws;
  unsigned short* selfb = (unsigned short*)p;
  p += (size_t)N_NODES * DIM * 2;
  unsigned short* neigh = (unsigned short*)p;
  p += (size_t)N_NODES * DIM * 2;
  unsigned* binned = (unsigned*)p;
  p += (size_t)NCH * SLOTS * 4;
  int* counts = (int*)p;
  p += (size_t)NCH * NBIN * 4;
  int* csr_cols = (int*)p;
  p += (size_t)NBIN * ENTCAP * 4;
  int* row_ptr = (int*)p;
  p += (size_t)N_NODES * 4;
  int* degs = (int*)p;
  p += (size_t)N_NODES * 4;
  int* fspillc = (int*)p;
  p += 4096;
  int2* fspill = (int2*)p;
  p += (size_t)NCH * FSPB * sizeof(int2);
  int* sspillc = (int*)p;
  p += 4096;
  int2* sspill = (int2*)p;
  p += (size_t)NBIN * SSPB * sizeof(int2);
  unsigned short* Wb = (unsigned short*)p;  // 64 KB

  // fill first (trailing blocks pre-convert W); then fused gemm+sort (both
  // depend only on fill); then agg.
  fill_kernel<<<NCH + 32, 256, 0, stream>>>(rows, cols, counts, binned,
                                            fspillc, fspill, n_edges, W1, W2,
                                            Wb);
  gemmsort_kernel<<<3 * NBIN, 256, 0, stream>>>(x, Wb, selfb, neigh, counts,
                                                binned, csr_cols, row_ptr,
                                                degs, sspillc, sspill);
  agg_kernel<<<2048, 256, 0, stream>>>(row_ptr, degs, csr_cols, neigh, selfb,
                                       fspillc, fspill, sspillc, sspill, out);
}